// Round 19
// baseline (56.005 us; speedup 1.0000x reference)
//
#include <hip/hip_runtime.h>
#include <cstdint>

typedef unsigned long long u64;
typedef unsigned int u32;

#define CLS_T    0.05f
#define T1G      0.997933f  // collect threshold: n ~ 406 +- 20 per class
#define TOPK     300
#define NWORDS   5          // ceil(300/64)
#define HBINS    2560
#define KEY_BASE 0x3D000000u
#define CCAP     512
#define NBLK     2048       // scan blocks
#define SCAP     16         // slots per (class, scan-block): 128B segment
#define OVBIT    0x80000000u
#define KMAX     (80 * TOPK)

__device__ inline u32 bin_of_bits(u32 bits) {
    u32 b = (bits - KEY_BASE) >> 14;
    if (b > (HBINS - 1)) b = HBINS - 1;
    return b;
}

// decode one anchor's box (identical arithmetic to reference)
__device__ inline float4 decode_box(const float* __restrict__ anc,
                                    const float* __restrict__ reg,
                                    u32 a, float W, float H)
{
    float x1 = anc[(size_t)a*4+0], y1 = anc[(size_t)a*4+1];
    float x2 = anc[(size_t)a*4+2], y2 = anc[(size_t)a*4+3];
    float w = x2 - x1, h = y2 - y1;
    float cx = x1 + 0.5f*w, cy = y1 + 0.5f*h;
    float r0 = reg[(size_t)a*4+0]*0.1f, r1 = reg[(size_t)a*4+1]*0.1f;
    float r2 = reg[(size_t)a*4+2]*0.2f, r3 = reg[(size_t)a*4+3]*0.2f;
    float pcx = cx + r0*w, pcy = cy + r1*h;
    float pw_ = expf(r2)*w, ph_ = expf(r3)*h;
    float4 b;
    b.x = fmaxf(pcx - 0.5f*pw_, 0.0f);
    b.y = fmaxf(pcy - 0.5f*ph_, 0.0f);
    b.z = fminf(pcx + 0.5f*pw_, W);
    b.w = fminf(pcy + 0.5f*ph_, H);
    return b;
}

// compare-exchange: keep max if (lo==up), else min  (descending bitonic)
__device__ inline void cex(u64& v, u64 p, bool lo, bool up) {
    u64 mx = v > p ? v : p;
    u64 mn = v > p ? p : v;
    v = (lo == up) ? mx : mn;
}
// in-wave stage (j <= 32): shfl_xor, barrier-free
__device__ inline void s1(u64& v, u32 tid, u32 kk, u32 j) {
    u64 p = __shfl_xor((unsigned long long)v, (int)j, 64);
    cex(v, p, (tid & j) == 0, (tid & kk) == 0);
}
// cross-wave stage (j >= 64): LDS exchange, 640-thread barrier-safe
__device__ inline void l1(u64* sm, u64& v, u32 tid, u32 kk, u32 j) {
    __syncthreads();
    if (tid < 512) sm[tid] = v;
    __syncthreads();
    if (tid < 512) {
        u64 p = sm[tid ^ j];
        cex(v, p, (tid & j) == 0, (tid & kk) == 0);
    }
}

// ---------------- standalone decode (fallback path only) ----------------
__global__ void decode_kernel(const float* __restrict__ anc,
                              const float* __restrict__ reg,
                              const int* __restrict__ ph,
                              const int* __restrict__ pw,
                              float* __restrict__ boxes,
                              u64* __restrict__ akey, int A)
{
    int a = blockIdx.x * blockDim.x + threadIdx.x;
    if (a >= A) return;
    akey[a] = 0;
    float W = (float)(*pw), H = (float)(*ph);
    float4 b = decode_box(anc, reg, (u32)a, W, H);
    boxes[a*4+0] = b.x; boxes[a*4+1] = b.y;
    boxes[a*4+2] = b.z; boxes[a*4+3] = b.w;
}

// ---------------- fused: zero akey + write output defaults + collect at T1 ----------------
__global__ __launch_bounds__(256) void fused_scan_kernel(
    const float* __restrict__ cls,
    u64* __restrict__ akey, float* __restrict__ out,
    u64* __restrict__ gbuf, u32* __restrict__ segcnt,
    u32* __restrict__ kcount, int A)
{
    const int tid = threadIdx.x;
    const int blk = blockIdx.x;

    if (blk == 0 && tid == 0) *kcount = 0;

    // defaults: scores 0, labels -1, boxes 0; zero akey
    float* scores = out;
    float* labels = out + A;
    float4* boxes4 = (float4*)(out + (size_t)2 * A);
    const float4 z4 = make_float4(0.f, 0.f, 0.f, 0.f);
    for (int a = blk * 256 + tid; a < A; a += NBLK * 256) {
        akey[a] = 0;
        scores[a] = 0.0f;
        labels[a] = -1.0f;
        boxes4[a] = z4;
    }

    __shared__ u32 cnt[80];
    __shared__ u64 buf[80][SCAP];
    __shared__ u32 s_over;
    for (int i = tid; i < 80; i += 256) cnt[i] = 0;
    if (tid == 0) s_over = 0;
    __syncthreads();

    size_t Nf4 = (size_t)A * 20;   // A*80/4
    const size_t stride = (size_t)NBLK * 256;
    const float4* p4 = (const float4*)cls;
    for (size_t i = (size_t)blk * 256 + tid; i < Nf4; i += 2 * stride) {
        float4 v0 = p4[i];
        size_t i1 = i + stride;
        bool has1 = (i1 < Nf4);
        float4 v1;
        if (has1) v1 = p4[i1];
        {
            float ss[4] = {v0.x, v0.y, v0.z, v0.w};
            #pragma unroll
            for (int q = 0; q < 4; ++q) {
                if (ss[q] > T1G) {
                    u32 flat = (u32)(i * 4 + q);
                    u32 a = flat / 80u;
                    u32 c = flat - a * 80u;
                    u32 p = atomicAdd(&cnt[c], 1u);
                    if (p < SCAP) buf[c][p] = ((u64)__float_as_uint(ss[q]) << 32) | (u32)(~a);
                    else s_over = 1;
                }
            }
        }
        if (has1) {
            float ss[4] = {v1.x, v1.y, v1.z, v1.w};
            #pragma unroll
            for (int q = 0; q < 4; ++q) {
                if (ss[q] > T1G) {
                    u32 flat = (u32)(i1 * 4 + q);
                    u32 a = flat / 80u;
                    u32 c = flat - a * 80u;
                    u32 p = atomicAdd(&cnt[c], 1u);
                    if (p < SCAP) buf[c][p] = ((u64)__float_as_uint(ss[q]) << 32) | (u32)(~a);
                    else s_over = 1;
                }
            }
        }
    }
    __syncthreads();

    const u32 ob = s_over ? OVBIT : 0u;
    for (int m = tid; m < 80 * SCAP; m += 256) {
        int c = m / SCAP, e = m - c * SCAP;
        u32 cc = cnt[c]; if (cc > SCAP) cc = SCAP;
        if ((u32)e < cc)
            gbuf[((size_t)c * NBLK + blk) * SCAP + e] = buf[c][e];
    }
    for (int c = tid; c < 80; c += 256) {
        u32 cc = cnt[c]; if (cc > SCAP) cc = SCAP;
        segcnt[(size_t)c * NBLK + blk] = cc | ob;
    }
}

// ---------------- fused per-class: wave prefix + direct gather + 512-sort + NMS + kept-list ----------------
__global__ __launch_bounds__(640) void class_fused_kernel(
    const u32* __restrict__ segcnt, const u64* __restrict__ gbuf,
    const float* __restrict__ cls,     // [A][C] for slow path
    const float* __restrict__ anc, const float* __restrict__ reg,
    const int* __restrict__ ph, const int* __restrict__ pw,
    u64* __restrict__ akey, u32* __restrict__ kcount, u32* __restrict__ klist,
    int A, int C)
{
    const int c = blockIdx.x;
    const u32 tid = threadIdx.x;
    const int lane = tid & 63;

    __shared__ u32 sh[HBINS];          // slow path histogram
    __shared__ u64 cand[CCAP];
    __shared__ u32 wtot[8], wob[8];
    __shared__ u32 s_sel, s_cnt, s_rem, s_base;
    __shared__ float4 sbox[TOPK];
    __shared__ float  sbar[TOPK];
    __shared__ u64 iomaskT[NWORDS][TOPK];
    __shared__ u64 s_keep[NWORDS];

    const float W = (float)(*pw), H = (float)(*ph);

    // ---- wave-structured prefix over this class's segcnt row (1 barrier) ----
    u32 v4[4] = {0,0,0,0};
    u32 s = 0, ob = 0;
    if (tid < 512) {
        const u32* row = segcnt + (size_t)c * NBLK;
        #pragma unroll
        for (int q = 0; q < 4; ++q) {
            u32 r = row[tid * 4 + q];
            ob |= r & OVBIT;
            v4[q] = r & ~OVBIT;
            s += v4[q];
        }
    }
    u32 incl = s;
    #pragma unroll
    for (int d = 1; d < 64; d <<= 1) {
        u32 t = __shfl_up(incl, d, 64);
        if ((tid & 63) >= (u32)d) incl += t;
    }
    u64 obm = __ballot(ob != 0);
    if (tid < 512 && (tid & 63) == 63) {
        wtot[tid >> 6] = incl;
        wob [tid >> 6] = (obm != 0) ? 1u : 0u;
    }
    __syncthreads();
    u32 woff = 0, ntot = 0, obt = 0;
    #pragma unroll
    for (int w2 = 0; w2 < 8; ++w2) {
        u32 t = wtot[w2];
        obt |= wob[w2];
        if (w2 < (int)(tid >> 6)) woff += t;
        ntot += t;
    }
    const u32 n = ntot;
    const bool over = (obt != 0);

    u32 cnt_f = 0;
    bool fast_ok = false;

    if (!over && n >= TOPK && n <= CCAP) {
        // direct gather: each prefix thread copies its own 4 segments (base in registers)
        if (tid < 512) {
            u32 base = woff + incl - s;
            #pragma unroll
            for (int q = 0; q < 4; ++q) {
                const u64* src = gbuf + ((size_t)c * NBLK + tid * 4 + q) * SCAP;
                for (u32 e = 0; e < v4[q]; ++e) cand[base + e] = src[e];
                base += v4[q];
            }
        }
        cnt_f = n;
        fast_ok = true;
    }

    if (!fast_ok) {
        // ---- slow exact path: 2-level select over the class column ----
        __syncthreads();
        for (int i = tid; i < HBINS; i += 640) sh[i] = 0;
        if (tid == 0) s_cnt = 0;
        __syncthreads();
        for (int a = tid; a < A; a += 640) {
            float sc = cls[(size_t)a * C + c];
            if (sc > CLS_T) atomicAdd(&sh[bin_of_bits(__float_as_uint(sc))], 1u);
        }
        __syncthreads();
        if (tid == 0) {
            u32 cum = 0; int sel = 0;
            for (int d = HBINS - 1; d >= 0; --d) {
                u32 nc = cum + sh[d];
                if (nc >= TOPK) { sel = d; break; }
                cum = nc;
            }
            s_sel = (u32)sel; s_rem = TOPK - cum;
        }
        __syncthreads();
        const u32 sel1 = s_sel;
        __syncthreads();
        for (int i = tid; i < 256; i += 640) sh[i] = 0;
        __syncthreads();
        for (int a = tid; a < A; a += 640) {
            float sc = cls[(size_t)a * C + c];
            if (sc > CLS_T) {
                u32 k = __float_as_uint(sc) - KEY_BASE;
                u32 b = k >> 14; if (b >= HBINS) b = HBINS - 1;
                if (b == sel1) atomicAdd(&sh[(k >> 6) & 0xFF], 1u);
            }
        }
        __syncthreads();
        if (tid == 0) {
            u32 rem = s_rem, cum = 0; int sel = 0;
            for (int d = 255; d >= 0; --d) {
                u32 nc = cum + sh[d];
                if (nc >= rem) { sel = d; break; }
                cum = nc;
            }
            s_sel = (sel1 << 14) | ((u32)sel << 6);
            s_cnt = 0;
        }
        __syncthreads();
        const u32 thresh = s_sel;
        for (int a = tid; a < A; a += 640) {
            float sc = cls[(size_t)a * C + c];
            if (sc > CLS_T) {
                u32 bits = __float_as_uint(sc);
                if (bits - KEY_BASE >= thresh) {
                    u32 p = atomicAdd(&s_cnt, 1u);
                    if (p < CCAP) cand[p] = ((u64)bits << 32) | (u32)(~(u32)a);
                }
            }
        }
        __syncthreads();
        cnt_f = s_cnt < CCAP ? s_cnt : CCAP;
    }

    // pad + zero iomaskT, one barrier
    for (u32 i = cnt_f + tid; i < CCAP; i += 640) cand[i] = 0;
    for (int m = tid; m < NWORDS * TOPK; m += 640) ((u64*)iomaskT)[m] = 0;
    __syncthreads();

    // ---- 512-element bitonic sort, 1 elem/thread, descending ----
    u64 v = 0;
    if (tid < 512) {
        v = cand[tid];
        for (u32 kk = 2; kk <= 64; kk <<= 1)
            for (u32 j = kk >> 1; j >= 1; j >>= 1)
                s1(v, tid, kk, j);
    }
    l1(cand, v, tid, 128u, 64u);
    if (tid < 512) for (u32 j = 32; j >= 1; j >>= 1) s1(v, tid, 128u, j);
    l1(cand, v, tid, 256u, 128u);
    l1(cand, v, tid, 256u, 64u);
    if (tid < 512) for (u32 j = 32; j >= 1; j >>= 1) s1(v, tid, 256u, j);
    l1(cand, v, tid, 512u, 256u);
    l1(cand, v, tid, 512u, 128u);
    l1(cand, v, tid, 512u, 64u);
    if (tid < 512) for (u32 j = 32; j >= 1; j >>= 1) s1(v, tid, 512u, j);
    // thread tid<512 holds sorted element tid in v

    const int T = (int)(cnt_f < TOPK ? cnt_f : TOPK);

    // ---- inline decode boxes for my candidate ----
    u64 key = v; u32 aidx = 0;
    if ((int)tid < T) {
        aidx = ~(u32)(key & 0xFFFFFFFFull);
        float4 b4 = decode_box(anc, reg, aidx, W, H);
        sbox[tid] = b4;
        sbar[tid] = fmaxf(b4.z - b4.x, 0.0f) * fmaxf(b4.w - b4.y, 0.0f);
    }
    __syncthreads();

    // ---- colmask: row jj, parity p, branchless IoU ----
    {
        const int jj = (int)(tid < 320 ? tid : tid - 320);
        const int p  = (int)(tid < 320 ? 0 : 1);
        if (jj < T) {
            float4 b = sbox[jj];
            float ar = sbar[jj];
            u64 cm[NWORDS] = {0,0,0,0,0};
            for (int i = p; i < jj; i += 2) {
                float4 bi = sbox[i];
                float iw = fmaxf(fminf(b.z, bi.z) - fmaxf(b.x, bi.x), 0.0f);
                float ih = fmaxf(fminf(b.w, bi.w) - fmaxf(b.y, bi.y), 0.0f);
                float inter = iw * ih;
                float uni = ((ar + sbar[i]) - inter) + 1e-8f;
                if (inter / uni > 0.5f) cm[i >> 6] |= 1ull << (i & 63);
            }
            #pragma unroll
            for (int w = 0; w < NWORDS; ++w)
                if (cm[w]) atomicOr(&iomaskT[w][jj], cm[w]);
        }
    }
    __syncthreads();

    // ---- wave 0: word-serial, round-parallel ballot greedy ----
    if (tid < 64) {
        u64 K[NWORDS];
        #pragma unroll
        for (int w = 0; w < NWORDS; ++w) {
            int b = w * 64 + lane;
            bool valid = (b < T);
            u64 cmw = 0, se = 0;
            if (valid) {
                #pragma unroll
                for (int w2 = 0; w2 < NWORDS; ++w2)
                    if (w2 < w) se |= K[w2] & iomaskT[w2][b];
                cmw = iomaskT[w][b];
            }
            u64 U = __ballot(valid && se == 0);
            u64 Kw = 0;
            int guard = 0;
            while (U && guard++ < 64) {
                u64 newk = __ballot(((U >> lane) & 1ull) && ((cmw & U) == 0));
                Kw |= newk; U &= ~newk;
                u64 supp = __ballot((cmw & Kw) != 0);
                U &= ~supp;
            }
            K[w] = Kw;
        }
        if (lane == 0) {
            #pragma unroll
            for (int w = 0; w < NWORDS; ++w) s_keep[w] = K[w];
        }
    }
    __syncthreads();

    // reserve kept-list range (one atomic per block)
    if (tid == 0) {
        u32 tot = 0;
        #pragma unroll
        for (int w = 0; w < NWORDS; ++w) tot += (u32)__popcll(s_keep[w]);
        s_base = atomicAdd(kcount, tot);
    }
    __syncthreads();

    if ((int)tid < T) {
        int w = (int)(tid >> 6), b = (int)(tid & 63);
        if ((s_keep[w] >> b) & 1ull) {
            u32 sbits = (u32)(key >> 32);
            u64 outk = ((u64)sbits << 32) | (u32)(255 - c);
            atomicMax(&akey[aidx], outk);
            u32 rank = 0;
            #pragma unroll
            for (int w2 = 0; w2 < NWORDS; ++w2)
                if (w2 < w) rank += (u32)__popcll(s_keep[w2]);
            rank += (u32)__popcll(s_keep[w] & ((b == 0) ? 0ull : ((1ull << b) - 1ull)));
            klist[s_base + rank] = aidx;
        }
    }
}

// ---------------- finalize-lite: write outputs for kept anchors only ----------------
__global__ void finalize_lite_kernel(const u32* __restrict__ kcount,
                                     const u32* __restrict__ klist,
                                     const u64* __restrict__ akey,
                                     const float* __restrict__ anc,
                                     const float* __restrict__ reg,
                                     const int* __restrict__ ph,
                                     const int* __restrict__ pw,
                                     float* __restrict__ out, int A)
{
    u32 i = blockIdx.x * blockDim.x + threadIdx.x;
    u32 kc = *kcount; if (kc > KMAX) kc = KMAX;
    if (i >= kc) return;
    u32 a = klist[i];
    u64 k = akey[a];
    float* scores = out;
    float* labels = out + A;
    float* boxes  = out + (size_t)2 * A;
    scores[a] = __uint_as_float((u32)(k >> 32));
    labels[a] = (float)(int)(255u - (u32)(k & 0xFFFFFFFFull));
    float W = (float)(*pw), H = (float)(*ph);
    float4 b = decode_box(anc, reg, a, W, H);
    boxes[(size_t)a*4+0] = b.x; boxes[(size_t)a*4+1] = b.y;
    boxes[(size_t)a*4+2] = b.z; boxes[(size_t)a*4+3] = b.w;
}

// ---------------- fallback finalize (boxes precomputed in out) ----------------
__global__ void fb_finalize_kernel(const u64* __restrict__ akey,
                                   float* __restrict__ out, int A)
{
    int a = blockIdx.x * blockDim.x + threadIdx.x;
    if (a >= A) return;
    float* scores = out;
    float* labels = out + A;
    float* boxes  = out + (size_t)2 * A;
    u64 k = akey[a];
    if (k) {
        scores[a] = __uint_as_float((u32)(k >> 32));
        labels[a] = (float)(int)(255u - (u32)(k & 0xFFFFFFFFull));
    } else {
        scores[a] = 0.0f;
        labels[a] = -1.0f;
        boxes[(size_t)a*4+0] = 0.0f;
        boxes[(size_t)a*4+1] = 0.0f;
        boxes[(size_t)a*4+2] = 0.0f;
        boxes[(size_t)a*4+3] = 0.0f;
    }
}

// ---------------- fallback (generic C / small ws): round-1 proven kernel ----------------
#define FB_CAP 1024
__global__ __launch_bounds__(256) void fb_topk_nms_kernel(
    const float* __restrict__ cls,
    const float* __restrict__ boxes,
    u64* __restrict__ akey,
    int A, int C)
{
    const int c   = blockIdx.x;
    const int tid = threadIdx.x;

    __shared__ u32 hist[HBINS];
    __shared__ u64 cand[FB_CAP];
    __shared__ float bx1[TOPK], by1[TOPK], bx2[TOPK], by2[TOPK], bar[TOPK];
    __shared__ u64 iomask[TOPK][NWORDS];
    __shared__ u64 keepm[NWORDS];
    __shared__ u32 s_sel1, s_sel2, s_rem, s_cnt;

    for (int i = tid; i < HBINS; i += 256) hist[i] = 0;
    __syncthreads();
    for (int a = tid; a < A; a += 256) {
        float s = cls[(size_t)a * C + c];
        if (s > CLS_T) {
            u32 k = __float_as_uint(s) - KEY_BASE;
            u32 b = k >> 14; if (b >= HBINS) b = HBINS - 1;
            atomicAdd(&hist[b], 1u);
        }
    }
    __syncthreads();
    if (tid == 0) {
        u32 cum = 0; int sel = 0;
        for (int d = HBINS - 1; d >= 0; --d) {
            u32 nc = cum + hist[d];
            if (nc >= TOPK) { sel = d; break; }
            cum = nc;
        }
        s_sel1 = (u32)sel; s_rem = TOPK - cum;
    }
    __syncthreads();
    const u32 sel1 = s_sel1;

    for (int i = tid; i < 256; i += 256) hist[i] = 0;
    __syncthreads();
    for (int a = tid; a < A; a += 256) {
        float s = cls[(size_t)a * C + c];
        if (s > CLS_T) {
            u32 k = __float_as_uint(s) - KEY_BASE;
            u32 b = k >> 14; if (b >= HBINS) b = HBINS - 1;
            if (b == sel1) atomicAdd(&hist[(k >> 6) & 0xFF], 1u);
        }
    }
    __syncthreads();
    if (tid == 0) {
        u32 rem = s_rem, cum = 0; int sel = 0;
        for (int d = 255; d >= 0; --d) {
            u32 nc = cum + hist[d];
            if (nc >= rem) { sel = d; break; }
            cum = nc;
        }
        s_sel2 = (u32)sel; s_cnt = 0;
    }
    __syncthreads();
    const u32 thresh = (sel1 << 14) | (s_sel2 << 6);

    for (int a = tid; a < A; a += 256) {
        float s = cls[(size_t)a * C + c];
        if (s > CLS_T) {
            u32 bits = __float_as_uint(s);
            u32 k = bits - KEY_BASE;
            if (k >= thresh) {
                u32 pos = atomicAdd(&s_cnt, 1u);
                if (pos < FB_CAP) cand[pos] = ((u64)bits << 32) | (u32)(~(u32)a);
            }
        }
    }
    __syncthreads();
    const u32 total = s_cnt < FB_CAP ? s_cnt : FB_CAP;
    for (int i = tid; i < FB_CAP; i += 256)
        if (i >= (int)total) cand[i] = 0;
    __syncthreads();

    for (u32 kk = 2; kk <= FB_CAP; kk <<= 1) {
        for (u32 j = kk >> 1; j > 0; j >>= 1) {
            for (u32 i = tid; i < FB_CAP; i += 256) {
                u32 l = i ^ j;
                if (l > i) {
                    u64 av = cand[i], bv = cand[l];
                    bool up = ((i & kk) == 0);
                    if ((up && av < bv) || (!up && av > bv)) { cand[i] = bv; cand[l] = av; }
                }
            }
            __syncthreads();
        }
    }
    const int T = (int)(total < TOPK ? total : TOPK);

    for (int i = tid; i < T; i += 256) {
        u32 a = ~(u32)(cand[i] & 0xFFFFFFFFull);
        float x1 = boxes[(size_t)a*4+0], y1 = boxes[(size_t)a*4+1];
        float x2 = boxes[(size_t)a*4+2], y2 = boxes[(size_t)a*4+3];
        bx1[i] = x1; by1[i] = y1; bx2[i] = x2; by2[i] = y2;
        bar[i] = fmaxf(x2 - x1, 0.0f) * fmaxf(y2 - y1, 0.0f);
    }
    __syncthreads();

    for (int i = tid; i < T; i += 256) {
        u64 m[NWORDS] = {0,0,0,0,0};
        float x1 = bx1[i], y1 = by1[i], x2 = bx2[i], y2 = by2[i], ai = bar[i];
        for (int j = i + 1; j < T; ++j) {
            float iw = fmaxf(fminf(x2, bx2[j]) - fmaxf(x1, bx1[j]), 0.0f);
            float ih = fmaxf(fminf(y2, by2[j]) - fmaxf(y1, by1[j]), 0.0f);
            float inter = iw * ih;
            float uni = ((ai + bar[j]) - inter) + 1e-8f;
            if (inter / uni > 0.5f) m[j >> 6] |= 1ull << (j & 63);
        }
        for (int k2 = 0; k2 < NWORDS; ++k2) iomask[i][k2] = m[k2];
    }
    __syncthreads();

    if (tid == 0) {
        u64 sup[NWORDS] = {0,0,0,0,0};
        u64 kp [NWORDS] = {0,0,0,0,0};
        for (int i = 0; i < T; ++i) {
            if (!((sup[i >> 6] >> (i & 63)) & 1ull)) {
                kp[i >> 6] |= 1ull << (i & 63);
                for (int k2 = 0; k2 < NWORDS; ++k2) sup[k2] |= iomask[i][k2];
            }
        }
        for (int k2 = 0; k2 < NWORDS; ++k2) keepm[k2] = kp[k2];
    }
    __syncthreads();

    for (int i = tid; i < T; i += 256) {
        if ((keepm[i >> 6] >> (i & 63)) & 1ull) {
            u64 key = cand[i];
            u32 a = ~(u32)(key & 0xFFFFFFFFull);
            u32 sbits = (u32)(key >> 32);
            u64 outk = ((u64)sbits << 32) | (u32)(255 - c);
            atomicMax(&akey[a], outk);
        }
    }
}

extern "C" void kernel_launch(void* const* d_in, const int* in_sizes, int n_in,
                              void* d_out, int out_size, void* d_ws, size_t ws_size,
                              hipStream_t stream) {
    const float* cls = (const float*)d_in[0];
    const float* reg = (const float*)d_in[1];
    const float* anc = (const float*)d_in[2];
    const int*   ph  = (const int*)d_in[3];
    const int*   pw  = (const int*)d_in[4];

    int A = in_sizes[2] / 4;
    int C = in_sizes[0] / A;

    float* out       = (float*)d_out;
    float* out_boxes = out + (size_t)2 * A;

    // workspace: akey | kcount | klist | segcnt | gbuf
    size_t akey_bytes = (size_t)A * sizeof(u64);
    size_t off_kc     = (akey_bytes + 255) & ~(size_t)255;
    size_t off_kl     = (off_kc + 256 + 255) & ~(size_t)255;
    size_t kl_bytes   = (size_t)KMAX * sizeof(u32);
    size_t off_sc     = (off_kl + kl_bytes + 255) & ~(size_t)255;
    size_t sc_bytes   = (size_t)80 * NBLK * sizeof(u32);
    size_t off_gb     = (off_sc + sc_bytes + 255) & ~(size_t)255;
    size_t gb_bytes   = (size_t)80 * NBLK * SCAP * sizeof(u64);
    size_t need       = off_gb + gb_bytes;

    u64* akey = (u64*)d_ws;

    bool fastpath = (C == 80) && ((A & 3) == 0) && (A < (1 << 20)) && (ws_size >= need);

    if (fastpath) {
        u32* kcount = (u32*)((char*)d_ws + off_kc);
        u32* klist  = (u32*)((char*)d_ws + off_kl);
        u32* segcnt = (u32*)((char*)d_ws + off_sc);
        u64* gbuf   = (u64*)((char*)d_ws + off_gb);

        fused_scan_kernel<<<NBLK, 256, 0, stream>>>(cls, akey, out, gbuf, segcnt, kcount, A);
        class_fused_kernel<<<C, 640, 0, stream>>>(segcnt, gbuf, cls, anc, reg, ph, pw,
                                                  akey, kcount, klist, A, C);
        finalize_lite_kernel<<<(KMAX + 255) / 256, 256, 0, stream>>>(kcount, klist, akey,
                                                                     anc, reg, ph, pw, out, A);
    } else {
        decode_kernel<<<(A + 255) / 256, 256, 0, stream>>>(anc, reg, ph, pw, out_boxes, akey, A);
        fb_topk_nms_kernel<<<C, 256, 0, stream>>>(cls, out_boxes, akey, A, C);
        fb_finalize_kernel<<<(A + 255) / 256, 256, 0, stream>>>(akey, out, A);
    }
}

// Round 20
// 52.031 us; speedup vs baseline: 1.0764x; 1.0764x over previous
//
#include <hip/hip_runtime.h>
#include <cstdint>

typedef unsigned long long u64;
typedef unsigned int u32;

#define CLS_T    0.05f
#define T1G      0.997933f  // collect threshold: n ~ 406 +- 20 per class
#define TOPK     300
#define NWORDS   5          // ceil(300/64)
#define HBINS    2560
#define KEY_BASE 0x3D000000u
#define CCAP     512
#define NBLK     2048       // scan blocks
#define SCAP     16         // slots per (class, scan-block): 128B segment
#define OVBIT    0x80000000u

__device__ inline u32 bin_of_bits(u32 bits) {
    u32 b = (bits - KEY_BASE) >> 14;
    if (b > (HBINS - 1)) b = HBINS - 1;
    return b;
}

// decode one anchor's box (identical arithmetic to reference)
__device__ inline float4 decode_box(const float* __restrict__ anc,
                                    const float* __restrict__ reg,
                                    u32 a, float W, float H)
{
    float x1 = anc[(size_t)a*4+0], y1 = anc[(size_t)a*4+1];
    float x2 = anc[(size_t)a*4+2], y2 = anc[(size_t)a*4+3];
    float w = x2 - x1, h = y2 - y1;
    float cx = x1 + 0.5f*w, cy = y1 + 0.5f*h;
    float r0 = reg[(size_t)a*4+0]*0.1f, r1 = reg[(size_t)a*4+1]*0.1f;
    float r2 = reg[(size_t)a*4+2]*0.2f, r3 = reg[(size_t)a*4+3]*0.2f;
    float pcx = cx + r0*w, pcy = cy + r1*h;
    float pw_ = expf(r2)*w, ph_ = expf(r3)*h;
    float4 b;
    b.x = fmaxf(pcx - 0.5f*pw_, 0.0f);
    b.y = fmaxf(pcy - 0.5f*ph_, 0.0f);
    b.z = fminf(pcx + 0.5f*pw_, W);
    b.w = fminf(pcy + 0.5f*ph_, H);
    return b;
}

// compare-exchange: keep max if (lo==up), else min  (descending bitonic)
__device__ inline void cex(u64& v, u64 p, bool lo, bool up) {
    u64 mx = v > p ? v : p;
    u64 mn = v > p ? p : v;
    v = (lo == up) ? mx : mn;
}
// in-wave stage (j <= 32): shfl_xor, barrier-free
__device__ inline void s1(u64& v, u32 tid, u32 kk, u32 j) {
    u64 p = __shfl_xor((unsigned long long)v, (int)j, 64);
    cex(v, p, (tid & j) == 0, (tid & kk) == 0);
}
// cross-wave stage (j >= 64): LDS exchange, 640-thread barrier-safe
__device__ inline void l1(u64* sm, u64& v, u32 tid, u32 kk, u32 j) {
    __syncthreads();
    if (tid < 512) sm[tid] = v;
    __syncthreads();
    if (tid < 512) {
        u64 p = sm[tid ^ j];
        cex(v, p, (tid & j) == 0, (tid & kk) == 0);
    }
}

// ---------------- standalone decode (fallback path only) ----------------
__global__ void decode_kernel(const float* __restrict__ anc,
                              const float* __restrict__ reg,
                              const int* __restrict__ ph,
                              const int* __restrict__ pw,
                              float* __restrict__ boxes,
                              u64* __restrict__ akey, int A)
{
    int a = blockIdx.x * blockDim.x + threadIdx.x;
    if (a >= A) return;
    akey[a] = 0;
    float W = (float)(*pw), H = (float)(*ph);
    float4 b = decode_box(anc, reg, (u32)a, W, H);
    boxes[a*4+0] = b.x; boxes[a*4+1] = b.y;
    boxes[a*4+2] = b.z; boxes[a*4+3] = b.w;
}

// ---------------- fused: zero akey + one-pass collect at T1 (2x MLP unroll) ----------------
__global__ __launch_bounds__(256) void fused_scan_kernel(
    const float* __restrict__ cls,
    u64* __restrict__ akey,
    u64* __restrict__ gbuf, u32* __restrict__ segcnt, int A)
{
    const int tid = threadIdx.x;
    const int blk = blockIdx.x;

    for (int a = blk * 256 + tid; a < A; a += NBLK * 256) akey[a] = 0;

    __shared__ u32 cnt[80];
    __shared__ u64 buf[80][SCAP];
    __shared__ u32 s_over;
    for (int i = tid; i < 80; i += 256) cnt[i] = 0;
    if (tid == 0) s_over = 0;
    __syncthreads();

    size_t Nf4 = (size_t)A * 20;   // A*80/4
    const size_t stride = (size_t)NBLK * 256;
    const float4* p4 = (const float4*)cls;
    for (size_t i = (size_t)blk * 256 + tid; i < Nf4; i += 2 * stride) {
        float4 v0 = p4[i];
        size_t i1 = i + stride;
        bool has1 = (i1 < Nf4);
        float4 v1;
        if (has1) v1 = p4[i1];
        {
            float ss[4] = {v0.x, v0.y, v0.z, v0.w};
            #pragma unroll
            for (int q = 0; q < 4; ++q) {
                if (ss[q] > T1G) {
                    u32 flat = (u32)(i * 4 + q);
                    u32 a = flat / 80u;
                    u32 c = flat - a * 80u;
                    u32 p = atomicAdd(&cnt[c], 1u);
                    if (p < SCAP) buf[c][p] = ((u64)__float_as_uint(ss[q]) << 32) | (u32)(~a);
                    else s_over = 1;
                }
            }
        }
        if (has1) {
            float ss[4] = {v1.x, v1.y, v1.z, v1.w};
            #pragma unroll
            for (int q = 0; q < 4; ++q) {
                if (ss[q] > T1G) {
                    u32 flat = (u32)(i1 * 4 + q);
                    u32 a = flat / 80u;
                    u32 c = flat - a * 80u;
                    u32 p = atomicAdd(&cnt[c], 1u);
                    if (p < SCAP) buf[c][p] = ((u64)__float_as_uint(ss[q]) << 32) | (u32)(~a);
                    else s_over = 1;
                }
            }
        }
    }
    __syncthreads();

    const u32 ob = s_over ? OVBIT : 0u;
    for (int m = tid; m < 80 * SCAP; m += 256) {
        int c = m / SCAP, e = m - c * SCAP;
        u32 cc = cnt[c]; if (cc > SCAP) cc = SCAP;
        if ((u32)e < cc)
            gbuf[((size_t)c * NBLK + blk) * SCAP + e] = buf[c][e];
    }
    for (int c = tid; c < 80; c += 256) {
        u32 cc = cnt[c]; if (cc > SCAP) cc = SCAP;
        segcnt[(size_t)c * NBLK + blk] = cc | ob;
    }
}

// ---------------- fused per-class: wave prefix + gather + 512-sort + decode + NMS ----------------
__global__ __launch_bounds__(640) void class_fused_kernel(
    const u32* __restrict__ segcnt, const u64* __restrict__ gbuf,
    const float* __restrict__ cls,     // [A][C] for slow path
    const float* __restrict__ anc, const float* __restrict__ reg,
    const int* __restrict__ ph, const int* __restrict__ pw,
    u64* __restrict__ akey, int A, int C)
{
    const int c = blockIdx.x;
    const u32 tid = threadIdx.x;
    const int lane = tid & 63;

    __shared__ u32 sh[HBINS];          // slow path histogram
    __shared__ u32 sp[NBLK];           // exclusive prefix of segment counts
    __shared__ u64 cand[CCAP];
    __shared__ u32 wtot[8], wob[8];
    __shared__ u32 s_sel, s_cnt, s_rem;
    __shared__ float4 sbox[TOPK];
    __shared__ float  sbar[TOPK];
    __shared__ u64 iomaskT[NWORDS][TOPK];
    __shared__ u64 s_keep[NWORDS];

    const float W = (float)(*pw), H = (float)(*ph);

    // ---- wave-structured prefix over this class's segcnt row (2 barriers) ----
    u32 v4[4] = {0,0,0,0};
    u32 s = 0, ob = 0;
    if (tid < 512) {
        const u32* row = segcnt + (size_t)c * NBLK;
        #pragma unroll
        for (int q = 0; q < 4; ++q) {
            u32 r = row[tid * 4 + q];
            ob |= r & OVBIT;
            v4[q] = r & ~OVBIT;
            s += v4[q];
        }
    }
    u32 incl = s;
    #pragma unroll
    for (int d = 1; d < 64; d <<= 1) {
        u32 t = __shfl_up(incl, d, 64);
        if ((tid & 63) >= (u32)d) incl += t;
    }
    u64 obm = __ballot(ob != 0);
    if (tid < 512 && (tid & 63) == 63) {
        wtot[tid >> 6] = incl;
        wob [tid >> 6] = (obm != 0) ? 1u : 0u;
    }
    __syncthreads();
    u32 woff = 0, ntot = 0, obt = 0;
    #pragma unroll
    for (int w2 = 0; w2 < 8; ++w2) {
        u32 t = wtot[w2];
        obt |= wob[w2];
        if (w2 < (int)(tid >> 6)) woff += t;
        ntot += t;
    }
    if (tid < 512) {
        u32 base = woff + incl - s;
        #pragma unroll
        for (int q = 0; q < 4; ++q) { sp[tid * 4 + q] = base; base += v4[q]; }
    }
    __syncthreads();
    const u32 n = ntot;
    const bool over = (obt != 0);

    u32 cnt_f = 0;
    bool fast_ok = false;

    if (!over && n >= TOPK && n <= CCAP) {
        // direct gather: dense index i -> (segment b, slot e) via binary search over sp
        for (u32 i = tid; i < n; i += 640) {
            int lo = 0, hi = NBLK;
            while (hi - lo > 1) {
                int mid = (lo + hi) >> 1;
                if (sp[mid] <= i) lo = mid; else hi = mid;
            }
            u32 e = i - sp[lo];
            cand[i] = gbuf[((size_t)c * NBLK + lo) * SCAP + e];
        }
        cnt_f = n;
        fast_ok = true;
    }

    if (!fast_ok) {
        // ---- slow exact path: 2-level select over the class column ----
        __syncthreads();
        for (int i = tid; i < HBINS; i += 640) sh[i] = 0;
        if (tid == 0) s_cnt = 0;
        __syncthreads();
        for (int a = tid; a < A; a += 640) {
            float sc = cls[(size_t)a * C + c];
            if (sc > CLS_T) atomicAdd(&sh[bin_of_bits(__float_as_uint(sc))], 1u);
        }
        __syncthreads();
        if (tid == 0) {
            u32 cum = 0; int sel = 0;
            for (int d = HBINS - 1; d >= 0; --d) {
                u32 nc = cum + sh[d];
                if (nc >= TOPK) { sel = d; break; }
                cum = nc;
            }
            s_sel = (u32)sel; s_rem = TOPK - cum;
        }
        __syncthreads();
        const u32 sel1 = s_sel;
        __syncthreads();
        for (int i = tid; i < 256; i += 640) sh[i] = 0;
        __syncthreads();
        for (int a = tid; a < A; a += 640) {
            float sc = cls[(size_t)a * C + c];
            if (sc > CLS_T) {
                u32 k = __float_as_uint(sc) - KEY_BASE;
                u32 b = k >> 14; if (b >= HBINS) b = HBINS - 1;
                if (b == sel1) atomicAdd(&sh[(k >> 6) & 0xFF], 1u);
            }
        }
        __syncthreads();
        if (tid == 0) {
            u32 rem = s_rem, cum = 0; int sel = 0;
            for (int d = 255; d >= 0; --d) {
                u32 nc = cum + sh[d];
                if (nc >= rem) { sel = d; break; }
                cum = nc;
            }
            s_sel = (sel1 << 14) | ((u32)sel << 6);
            s_cnt = 0;
        }
        __syncthreads();
        const u32 thresh = s_sel;
        for (int a = tid; a < A; a += 640) {
            float sc = cls[(size_t)a * C + c];
            if (sc > CLS_T) {
                u32 bits = __float_as_uint(sc);
                if (bits - KEY_BASE >= thresh) {
                    u32 p = atomicAdd(&s_cnt, 1u);
                    if (p < CCAP) cand[p] = ((u64)bits << 32) | (u32)(~(u32)a);
                }
            }
        }
        __syncthreads();
        cnt_f = s_cnt < CCAP ? s_cnt : CCAP;
    }

    // pad + zero iomaskT, one barrier
    for (u32 i = cnt_f + tid; i < CCAP; i += 640) cand[i] = 0;
    for (int m = tid; m < NWORDS * TOPK; m += 640) ((u64*)iomaskT)[m] = 0;
    __syncthreads();

    // ---- 512-element bitonic sort, 1 elem/thread, descending ----
    u64 v = 0;
    if (tid < 512) {
        v = cand[tid];
        for (u32 kk = 2; kk <= 64; kk <<= 1)
            for (u32 j = kk >> 1; j >= 1; j >>= 1)
                s1(v, tid, kk, j);
    }
    l1(cand, v, tid, 128u, 64u);
    if (tid < 512) for (u32 j = 32; j >= 1; j >>= 1) s1(v, tid, 128u, j);
    l1(cand, v, tid, 256u, 128u);
    l1(cand, v, tid, 256u, 64u);
    if (tid < 512) for (u32 j = 32; j >= 1; j >>= 1) s1(v, tid, 256u, j);
    l1(cand, v, tid, 512u, 256u);
    l1(cand, v, tid, 512u, 128u);
    l1(cand, v, tid, 512u, 64u);
    if (tid < 512) for (u32 j = 32; j >= 1; j >>= 1) s1(v, tid, 512u, j);
    // thread tid<512 holds sorted element tid in v

    const int T = (int)(cnt_f < TOPK ? cnt_f : TOPK);

    // ---- inline decode boxes for my candidate ----
    u64 key = v; u32 aidx = 0;
    if ((int)tid < T) {
        aidx = ~(u32)(key & 0xFFFFFFFFull);
        float4 b4 = decode_box(anc, reg, aidx, W, H);
        sbox[tid] = b4;
        sbar[tid] = fmaxf(b4.z - b4.x, 0.0f) * fmaxf(b4.w - b4.y, 0.0f);
    }
    __syncthreads();

    // ---- colmask: row jj, parity p, branchless IoU ----
    {
        const int jj = (int)(tid < 320 ? tid : tid - 320);
        const int p  = (int)(tid < 320 ? 0 : 1);
        if (jj < T) {
            float4 b = sbox[jj];
            float ar = sbar[jj];
            u64 cm[NWORDS] = {0,0,0,0,0};
            for (int i = p; i < jj; i += 2) {
                float4 bi = sbox[i];
                float iw = fmaxf(fminf(b.z, bi.z) - fmaxf(b.x, bi.x), 0.0f);
                float ih = fmaxf(fminf(b.w, bi.w) - fmaxf(b.y, bi.y), 0.0f);
                float inter = iw * ih;
                float uni = ((ar + sbar[i]) - inter) + 1e-8f;
                if (inter / uni > 0.5f) cm[i >> 6] |= 1ull << (i & 63);
            }
            #pragma unroll
            for (int w = 0; w < NWORDS; ++w)
                if (cm[w]) atomicOr(&iomaskT[w][jj], cm[w]);
        }
    }
    __syncthreads();

    // ---- wave 0: word-serial, round-parallel ballot greedy ----
    if (tid < 64) {
        u64 K[NWORDS];
        #pragma unroll
        for (int w = 0; w < NWORDS; ++w) {
            int b = w * 64 + lane;
            bool valid = (b < T);
            u64 cmw = 0, se = 0;
            if (valid) {
                #pragma unroll
                for (int w2 = 0; w2 < NWORDS; ++w2)
                    if (w2 < w) se |= K[w2] & iomaskT[w2][b];
                cmw = iomaskT[w][b];
            }
            u64 U = __ballot(valid && se == 0);
            u64 Kw = 0;
            int guard = 0;
            while (U && guard++ < 64) {
                u64 newk = __ballot(((U >> lane) & 1ull) && ((cmw & U) == 0));
                Kw |= newk; U &= ~newk;
                u64 supp = __ballot((cmw & Kw) != 0);
                U &= ~supp;
            }
            K[w] = Kw;
        }
        if (lane == 0) {
            #pragma unroll
            for (int w = 0; w < NWORDS; ++w) s_keep[w] = K[w];
        }
    }
    __syncthreads();

    if ((int)tid < T) {
        if ((s_keep[tid >> 6] >> (tid & 63)) & 1ull) {
            u32 sbits = (u32)(key >> 32);
            u64 outk = ((u64)sbits << 32) | (u32)(255 - c);
            atomicMax(&akey[aidx], outk);
        }
    }
}

// ---------------- finalize: decode kept boxes inline ----------------
__global__ void finalize_kernel(const u64* __restrict__ akey,
                                const float* __restrict__ anc,
                                const float* __restrict__ reg,
                                const int* __restrict__ ph,
                                const int* __restrict__ pw,
                                float* __restrict__ out, int A)
{
    int a = blockIdx.x * blockDim.x + threadIdx.x;
    if (a >= A) return;
    float* scores = out;
    float* labels = out + A;
    float* boxes  = out + (size_t)2 * A;
    u64 k = akey[a];
    if (k) {
        scores[a] = __uint_as_float((u32)(k >> 32));
        labels[a] = (float)(int)(255u - (u32)(k & 0xFFFFFFFFull));
        float W = (float)(*pw), H = (float)(*ph);
        float4 b = decode_box(anc, reg, (u32)a, W, H);
        boxes[(size_t)a*4+0] = b.x; boxes[(size_t)a*4+1] = b.y;
        boxes[(size_t)a*4+2] = b.z; boxes[(size_t)a*4+3] = b.w;
    } else {
        scores[a] = 0.0f;
        labels[a] = -1.0f;
        boxes[(size_t)a*4+0] = 0.0f;
        boxes[(size_t)a*4+1] = 0.0f;
        boxes[(size_t)a*4+2] = 0.0f;
        boxes[(size_t)a*4+3] = 0.0f;
    }
}

// ---------------- fallback finalize (boxes precomputed in out) ----------------
__global__ void fb_finalize_kernel(const u64* __restrict__ akey,
                                   float* __restrict__ out, int A)
{
    int a = blockIdx.x * blockDim.x + threadIdx.x;
    if (a >= A) return;
    float* scores = out;
    float* labels = out + A;
    float* boxes  = out + (size_t)2 * A;
    u64 k = akey[a];
    if (k) {
        scores[a] = __uint_as_float((u32)(k >> 32));
        labels[a] = (float)(int)(255u - (u32)(k & 0xFFFFFFFFull));
    } else {
        scores[a] = 0.0f;
        labels[a] = -1.0f;
        boxes[(size_t)a*4+0] = 0.0f;
        boxes[(size_t)a*4+1] = 0.0f;
        boxes[(size_t)a*4+2] = 0.0f;
        boxes[(size_t)a*4+3] = 0.0f;
    }
}

// ---------------- fallback (generic C / small ws): round-1 proven kernel ----------------
#define FB_CAP 1024
__global__ __launch_bounds__(256) void fb_topk_nms_kernel(
    const float* __restrict__ cls,
    const float* __restrict__ boxes,
    u64* __restrict__ akey,
    int A, int C)
{
    const int c   = blockIdx.x;
    const int tid = threadIdx.x;

    __shared__ u32 hist[HBINS];
    __shared__ u64 cand[FB_CAP];
    __shared__ float bx1[TOPK], by1[TOPK], bx2[TOPK], by2[TOPK], bar[TOPK];
    __shared__ u64 iomask[TOPK][NWORDS];
    __shared__ u64 keepm[NWORDS];
    __shared__ u32 s_sel1, s_sel2, s_rem, s_cnt;

    for (int i = tid; i < HBINS; i += 256) hist[i] = 0;
    __syncthreads();
    for (int a = tid; a < A; a += 256) {
        float s = cls[(size_t)a * C + c];
        if (s > CLS_T) {
            u32 k = __float_as_uint(s) - KEY_BASE;
            u32 b = k >> 14; if (b >= HBINS) b = HBINS - 1;
            atomicAdd(&hist[b], 1u);
        }
    }
    __syncthreads();
    if (tid == 0) {
        u32 cum = 0; int sel = 0;
        for (int d = HBINS - 1; d >= 0; --d) {
            u32 nc = cum + hist[d];
            if (nc >= TOPK) { sel = d; break; }
            cum = nc;
        }
        s_sel1 = (u32)sel; s_rem = TOPK - cum;
    }
    __syncthreads();
    const u32 sel1 = s_sel1;

    for (int i = tid; i < 256; i += 256) hist[i] = 0;
    __syncthreads();
    for (int a = tid; a < A; a += 256) {
        float s = cls[(size_t)a * C + c];
        if (s > CLS_T) {
            u32 k = __float_as_uint(s) - KEY_BASE;
            u32 b = k >> 14; if (b >= HBINS) b = HBINS - 1;
            if (b == sel1) atomicAdd(&hist[(k >> 6) & 0xFF], 1u);
        }
    }
    __syncthreads();
    if (tid == 0) {
        u32 rem = s_rem, cum = 0; int sel = 0;
        for (int d = 255; d >= 0; --d) {
            u32 nc = cum + hist[d];
            if (nc >= rem) { sel = d; break; }
            cum = nc;
        }
        s_sel2 = (u32)sel; s_cnt = 0;
    }
    __syncthreads();
    const u32 thresh = (sel1 << 14) | (s_sel2 << 6);

    for (int a = tid; a < A; a += 256) {
        float s = cls[(size_t)a * C + c];
        if (s > CLS_T) {
            u32 bits = __float_as_uint(s);
            u32 k = bits - KEY_BASE;
            if (k >= thresh) {
                u32 pos = atomicAdd(&s_cnt, 1u);
                if (pos < FB_CAP) cand[pos] = ((u64)bits << 32) | (u32)(~(u32)a);
            }
        }
    }
    __syncthreads();
    const u32 total = s_cnt < FB_CAP ? s_cnt : FB_CAP;
    for (int i = tid; i < FB_CAP; i += 256)
        if (i >= (int)total) cand[i] = 0;
    __syncthreads();

    for (u32 kk = 2; kk <= FB_CAP; kk <<= 1) {
        for (u32 j = kk >> 1; j > 0; j >>= 1) {
            for (u32 i = tid; i < FB_CAP; i += 256) {
                u32 l = i ^ j;
                if (l > i) {
                    u64 av = cand[i], bv = cand[l];
                    bool up = ((i & kk) == 0);
                    if ((up && av < bv) || (!up && av > bv)) { cand[i] = bv; cand[l] = av; }
                }
            }
            __syncthreads();
        }
    }
    const int T = (int)(total < TOPK ? total : TOPK);

    for (int i = tid; i < T; i += 256) {
        u32 a = ~(u32)(cand[i] & 0xFFFFFFFFull);
        float x1 = boxes[(size_t)a*4+0], y1 = boxes[(size_t)a*4+1];
        float x2 = boxes[(size_t)a*4+2], y2 = boxes[(size_t)a*4+3];
        bx1[i] = x1; by1[i] = y1; bx2[i] = x2; by2[i] = y2;
        bar[i] = fmaxf(x2 - x1, 0.0f) * fmaxf(y2 - y1, 0.0f);
    }
    __syncthreads();

    for (int i = tid; i < T; i += 256) {
        u64 m[NWORDS] = {0,0,0,0,0};
        float x1 = bx1[i], y1 = by1[i], x2 = bx2[i], y2 = by2[i], ai = bar[i];
        for (int j = i + 1; j < T; ++j) {
            float iw = fmaxf(fminf(x2, bx2[j]) - fmaxf(x1, bx1[j]), 0.0f);
            float ih = fmaxf(fminf(y2, by2[j]) - fmaxf(y1, by1[j]), 0.0f);
            float inter = iw * ih;
            float uni = ((ai + bar[j]) - inter) + 1e-8f;
            if (inter / uni > 0.5f) m[j >> 6] |= 1ull << (j & 63);
        }
        for (int k2 = 0; k2 < NWORDS; ++k2) iomask[i][k2] = m[k2];
    }
    __syncthreads();

    if (tid == 0) {
        u64 sup[NWORDS] = {0,0,0,0,0};
        u64 kp [NWORDS] = {0,0,0,0,0};
        for (int i = 0; i < T; ++i) {
            if (!((sup[i >> 6] >> (i & 63)) & 1ull)) {
                kp[i >> 6] |= 1ull << (i & 63);
                for (int k2 = 0; k2 < NWORDS; ++k2) sup[k2] |= iomask[i][k2];
            }
        }
        for (int k2 = 0; k2 < NWORDS; ++k2) keepm[k2] = kp[k2];
    }
    __syncthreads();

    for (int i = tid; i < T; i += 256) {
        if ((keepm[i >> 6] >> (i & 63)) & 1ull) {
            u64 key = cand[i];
            u32 a = ~(u32)(key & 0xFFFFFFFFull);
            u32 sbits = (u32)(key >> 32);
            u64 outk = ((u64)sbits << 32) | (u32)(255 - c);
            atomicMax(&akey[a], outk);
        }
    }
}

extern "C" void kernel_launch(void* const* d_in, const int* in_sizes, int n_in,
                              void* d_out, int out_size, void* d_ws, size_t ws_size,
                              hipStream_t stream) {
    const float* cls = (const float*)d_in[0];
    const float* reg = (const float*)d_in[1];
    const float* anc = (const float*)d_in[2];
    const int*   ph  = (const int*)d_in[3];
    const int*   pw  = (const int*)d_in[4];

    int A = in_sizes[2] / 4;
    int C = in_sizes[0] / A;

    float* out       = (float*)d_out;
    float* out_boxes = out + (size_t)2 * A;

    // workspace: akey | segcnt | gbuf
    size_t akey_bytes = (size_t)A * sizeof(u64);
    size_t off_sc     = (akey_bytes + 255) & ~(size_t)255;
    size_t sc_bytes   = (size_t)80 * NBLK * sizeof(u32);
    size_t off_gb     = (off_sc + sc_bytes + 255) & ~(size_t)255;
    size_t gb_bytes   = (size_t)80 * NBLK * SCAP * sizeof(u64);
    size_t need       = off_gb + gb_bytes;

    u64* akey = (u64*)d_ws;

    bool fastpath = (C == 80) && ((A & 3) == 0) && (A < (1 << 20)) && (ws_size >= need);

    if (fastpath) {
        u32* segcnt = (u32*)((char*)d_ws + off_sc);
        u64* gbuf   = (u64*)((char*)d_ws + off_gb);

        fused_scan_kernel<<<NBLK, 256, 0, stream>>>(cls, akey, gbuf, segcnt, A);
        class_fused_kernel<<<C, 640, 0, stream>>>(segcnt, gbuf, cls, anc, reg, ph, pw, akey, A, C);
        finalize_kernel<<<(A + 255) / 256, 256, 0, stream>>>(akey, anc, reg, ph, pw, out, A);
    } else {
        decode_kernel<<<(A + 255) / 256, 256, 0, stream>>>(anc, reg, ph, pw, out_boxes, akey, A);
        fb_topk_nms_kernel<<<C, 256, 0, stream>>>(cls, out_boxes, akey, A, C);
        fb_finalize_kernel<<<(A + 255) / 256, 256, 0, stream>>>(akey, out, A);
    }
}